// Round 1
// 63.290 us; speedup vs baseline: 1.1817x; 1.1817x over previous
//
#include <hip/hip_runtime.h>
#include <math.h>

#define MARGIN 0.1f
#define NN 512          // rows (fixed by setup_inputs)
#define DD 128          // embedding dim (fixed)
#define NT 512          // threads per block (== NN; 8 waves/CU)
#define AB 2            // anchors per block
#define GROUPS (NT / 4) // 128 row-groups of 4 lanes each
#define NTILES (NN / GROUPS)  // 4 row passes per thread
#define NBLK (NN / AB)  // 256 blocks = 1 per CU
#define MAXPOS 256

// R3 theory: the old 8-tile LDS staging had ZERO intra-block reuse (each
// staged float4 written once, read once) but cost 16 __syncthreads at
// 1 wave/SIMD occupancy -> pure latency serialization. This version reads
// embedding rows directly global->register (each 4-lane group covers a
// contiguous 64B line per issue), keeps the 2 anchor fragments in 16 float4
// registers, and runs the whole sim phase with NO barriers. NT 256->512
// doubles waves/SIMD for latency hiding. Barriers: 19 -> 4.
__global__ __launch_bounds__(NT) void triplet_partial_kernel(
        const float* __restrict__ emb, const int* __restrict__ labels,
        double* __restrict__ part_sum, int* __restrict__ part_cnt) {
    __shared__ int   lab[NN];
    __shared__ __align__(16) float ea[AB][DD];
    __shared__ float simr[AB][NN];
    __shared__ int   pos[AB][MAXPOS];
    __shared__ int   npos[AB];
    __shared__ double red_s[NT / 64];
    __shared__ int    red_c[NT / 64];

    const int b  = blockIdx.x;
    const int t  = threadIdx.x;
    const int a0 = b * AB;
    const int g  = t >> 2;   // row-group (0..127); row = tl*GROUPS + g
    const int ks = t & 3;    // k-slice; partners on adjacent lanes (xor 1,2)

    // labels + anchor rows to LDS (coalesced, one pass)
    lab[t] = labels[t];                       // NT == NN
    if (t < AB * DD) {                        // 256 threads load 2 anchor rows
        ea[t >> 7][t & 127] = emb[(size_t)(a0 + (t >> 7)) * DD + (t & 127)];
    }
    if (t < AB) npos[t] = 0;
    __syncthreads();

    const float4* __restrict__ emb4 = reinterpret_cast<const float4*>(emb);
    const float4* ea4 = reinterpret_cast<const float4*>(&ea[0][0]);

    // Anchor k-slices into registers. Thread handles k-elements
    // {16*i2 + 4*ks + c}: 4-float chunks -> float4 LDS reads, 4 distinct
    // 16B addrs/wave (banks 0..15), 16-way broadcast: conflict-free.
    float4 w0[8], w1[8];
    #pragma unroll
    for (int i2 = 0; i2 < 8; ++i2) {
        w0[i2] = ea4[i2 * 4 + ks];        // ea[0]
        w1[i2] = ea4[32 + i2 * 4 + ks];   // ea[1]
    }

    // anchor inverse norms: register sums + 2 shuffles
    float nsq0 = 0.f, nsq1 = 0.f;
    #pragma unroll
    for (int i2 = 0; i2 < 8; ++i2) {
        nsq0 += w0[i2].x * w0[i2].x + w0[i2].y * w0[i2].y
              + w0[i2].z * w0[i2].z + w0[i2].w * w0[i2].w;
        nsq1 += w1[i2].x * w1[i2].x + w1[i2].y * w1[i2].y
              + w1[i2].z * w1[i2].z + w1[i2].w * w1[i2].w;
    }
    nsq0 += __shfl_xor(nsq0, 1, 64); nsq0 += __shfl_xor(nsq0, 2, 64);
    nsq1 += __shfl_xor(nsq1, 1, 64); nsq1 += __shfl_xor(nsq1, 2, 64);
    const float inva0 = 1.0f / sqrtf(nsq0);
    const float inva1 = 1.0f / sqrtf(nsq1);

    // sim rows: direct global->register, no LDS tile, no barriers.
    // Per-group read pattern: 4 lanes x float4 (i2*4+ks) = contiguous 64B.
    #pragma unroll 2
    for (int tl = 0; tl < NTILES; ++tl) {
        const int r = tl * GROUPS + g;
        float4 v[8];
        #pragma unroll
        for (int i2 = 0; i2 < 8; ++i2)
            v[i2] = emb4[(size_t)r * 32 + i2 * 4 + ks];

        // two accumulator banks halve the FMA dependency chain
        float d0a = 0.f, d0b = 0.f, d1a = 0.f, d1b = 0.f, na = 0.f, nb = 0.f;
        #pragma unroll
        for (int i2 = 0; i2 < 8; i2 += 2) {
            d0a += v[i2].x * w0[i2].x + v[i2].y * w0[i2].y
                 + v[i2].z * w0[i2].z + v[i2].w * w0[i2].w;
            d1a += v[i2].x * w1[i2].x + v[i2].y * w1[i2].y
                 + v[i2].z * w1[i2].z + v[i2].w * w1[i2].w;
            na  += v[i2].x * v[i2].x + v[i2].y * v[i2].y
                 + v[i2].z * v[i2].z + v[i2].w * v[i2].w;
            const int j2 = i2 + 1;
            d0b += v[j2].x * w0[j2].x + v[j2].y * w0[j2].y
                 + v[j2].z * w0[j2].z + v[j2].w * w0[j2].w;
            d1b += v[j2].x * w1[j2].x + v[j2].y * w1[j2].y
                 + v[j2].z * w1[j2].z + v[j2].w * w1[j2].w;
            nb  += v[j2].x * v[j2].x + v[j2].y * v[j2].y
                 + v[j2].z * v[j2].z + v[j2].w * v[j2].w;
        }
        float d0 = d0a + d0b, d1 = d1a + d1b, nsq = na + nb;

        // reduce across the 4 k-slices (adjacent lanes, same wave)
        d0  += __shfl_xor(d0, 1, 64);  d0  += __shfl_xor(d0, 2, 64);
        d1  += __shfl_xor(d1, 1, 64);  d1  += __shfl_xor(d1, 2, 64);
        nsq += __shfl_xor(nsq, 1, 64); nsq += __shfl_xor(nsq, 2, 64);
        if (ks == 0) {
            const float rn = 1.0f / sqrtf(nsq);
            simr[0][r] = d0 * inva0 * rn;
            simr[1][r] = d1 * inva1 * rn;
        }
    }
    __syncthreads();

    // collect positives per anchor (one j per thread: NT == NN)
    {
        const int j = t;
        #pragma unroll
        for (int ai = 0; ai < AB; ++ai) {
            if (j != a0 + ai && lab[j] == lab[a0 + ai]) {
                int idx = atomicAdd(&npos[ai], 1);
                if (idx < MAXPOS) pos[ai][idx] = j;
            }
        }
    }
    __syncthreads();

    // semihard triplet partial: each thread owns one negative candidate n==t
    const int   myLab = lab[t];
    const float sn0   = simr[0][t];
    const float sn1   = simr[1][t];
    double lsum = 0.0;
    int    lcnt = 0;
    {
        const int la = lab[a0];
        if (myLab != la) {
            const int np = min(npos[0], MAXPOS);
            for (int pi = 0; pi < np; ++pi) {
                const float sap = simr[0][pos[0][pi]];  // wave-uniform broadcast
                const float d = sn0 - sap + MARGIN;
                if (d > 0.f)    lsum += (double)d;
                if (d > 1e-16f) lcnt += 1;
            }
        }
    }
    {
        const int la = lab[a0 + 1];
        if (myLab != la) {
            const int np = min(npos[1], MAXPOS);
            for (int pi = 0; pi < np; ++pi) {
                const float sap = simr[1][pos[1][pi]];
                const float d = sn1 - sap + MARGIN;
                if (d > 0.f)    lsum += (double)d;
                if (d > 1e-16f) lcnt += 1;
            }
        }
    }

    // wave shuffle reduce, then cross-wave via LDS
    for (int off = 32; off > 0; off >>= 1) {
        lsum += __shfl_down(lsum, off, 64);
        lcnt += __shfl_down(lcnt, off, 64);
    }
    const int wid = t >> 6, lane = t & 63;
    if (lane == 0) { red_s[wid] = lsum; red_c[wid] = lcnt; }
    __syncthreads();
    if (t == 0) {
        double s = 0.0; int c = 0;
        for (int w = 0; w < NT / 64; ++w) { s += red_s[w]; c += red_c[w]; }
        part_sum[b] = s;     // plain stores, distinct addresses — no atomics
        part_cnt[b] = c;
    }
}

__global__ __launch_bounds__(NBLK) void finalize_kernel(
        const double* __restrict__ part_sum, const int* __restrict__ part_cnt,
        float* __restrict__ out) {
    __shared__ double rs[NBLK / 64];
    __shared__ int    rc[NBLK / 64];
    const int t = threadIdx.x;
    double s = part_sum[t];
    int    c = part_cnt[t];
    for (int off = 32; off > 0; off >>= 1) {
        s += __shfl_down(s, off, 64);
        c += __shfl_down(c, off, 64);
    }
    const int wid = t >> 6, lane = t & 63;
    if (lane == 0) { rs[wid] = s; rc[wid] = c; }
    __syncthreads();
    if (t == 0) {
        double S = 0.0; int C = 0;
        for (int w = 0; w < NBLK / 64; ++w) { S += rs[w]; C += rc[w]; }
        out[0] = (float)(S / ((double)C + 1e-16));
    }
}

extern "C" void kernel_launch(void* const* d_in, const int* in_sizes, int n_in,
                              void* d_out, int out_size, void* d_ws, size_t ws_size,
                              hipStream_t stream) {
    const float* emb  = (const float*)d_in[0];
    const int* labels = (const int*)d_in[1];

    double* part_sum = (double*)d_ws;
    int*    part_cnt = (int*)((char*)d_ws + NBLK * sizeof(double));
    float*  out      = (float*)d_out;

    triplet_partial_kernel<<<NBLK, NT, 0, stream>>>(emb, labels, part_sum, part_cnt);
    finalize_kernel<<<1, NBLK, 0, stream>>>(part_sum, part_cnt, out);
}